// Round 13
// baseline (160.464 us; speedup 1.0000x reference)
//
#include <hip/hip_runtime.h>
#include <hip/hip_fp16.h>

#define DD 40
#define PITER 32   // edges per thread in pass A (chunk = 256*PITER = 8192)
#define NP 512     // dst partitions; one pass-B block owns one partition
#define SROW_LD 44 // padded LDS row stride for srow
#define SWT_LD 41  // padded sWT stride
#define GC_PAD 16  // gcur: one counter per 64B line
#define BAE (256 * PITER)  // 8192 edges per binA block

// ---------- Pass A: LDS-sorted binning; global writes are coalesced runs ----------
__global__ __launch_bounds__(256) void k_binA(
    const int* __restrict__ src, const int* __restrict__ dst,
    int* __restrict__ gcur, unsigned* __restrict__ ebin,
    int E, int PS, unsigned M, int CAPB) {
  __shared__ unsigned ssort[BAE];  // 32KB
  __shared__ int sdest[BAE];       // 32KB
  __shared__ int hist[NP];
  __shared__ int binstart[NP];
  __shared__ int curs[NP];
  __shared__ int win[NP];
  __shared__ int sbuf[2][256];
  const int tid = threadIdx.x;
  const int base = blockIdx.x * BAE;
  const int cnt = min(BAE, E - base);

  hist[tid] = 0;
  hist[tid + 256] = 0;
  __syncthreads();
  for (int it = 0; it < PITER; ++it) {
    int i = it * 256 + tid;
    if (i < cnt) {
      unsigned t = (unsigned)dst[base + i];
      int b = (int)(((unsigned long long)t * M) >> 31);
      atomicAdd(&hist[b], 1);
    }
  }
  __syncthreads();
  int h0 = hist[2 * tid], h1 = hist[2 * tid + 1];
  sbuf[0][tid] = h0 + h1;
  __syncthreads();
  int pi = 0;
  for (int off = 1; off < 256; off <<= 1) {
    int x = sbuf[pi][tid];
    if (tid >= off) x += sbuf[pi][tid - off];
    sbuf[pi ^ 1][tid] = x;
    __syncthreads();
    pi ^= 1;
  }
  int excl = sbuf[pi][tid] - (h0 + h1);
  binstart[2 * tid] = excl;
  binstart[2 * tid + 1] = excl + h0;
  curs[2 * tid] = excl;
  curs[2 * tid + 1] = excl + h0;
#pragma unroll
  for (int q = 0; q < 2; ++q) {
    int b = 2 * tid + q;
    int h = hist[b];
    win[b] = h ? (b * CAPB + atomicAdd(&gcur[b * GC_PAD], h)) : 0;
  }
  __syncthreads();
  for (int it = 0; it < PITER; ++it) {
    int i = it * 256 + tid;
    if (i < cnt) {
      unsigned t = (unsigned)dst[base + i];
      int b = (int)(((unsigned long long)t * M) >> 31);
      unsigned local = t - (unsigned)(b * PS);
      int pos = atomicAdd(&curs[b], 1);
      ssort[pos] = (local << 17) | (unsigned)src[base + i];
      sdest[pos] = win[b] + (pos - binstart[b]);
    }
  }
  __syncthreads();
  for (int k = tid; k < cnt; k += 256) ebin[sdest[k]] = ssort[k];  // coalesced runs
}

// ---------- Pass B: one block per partition; LDS count/scan/sort; emits dinv ----------
__global__ __launch_bounds__(256) void k_partB(
    const unsigned* __restrict__ ebin, const int* __restrict__ gcur,
    int* __restrict__ ideg, int* __restrict__ cursor, float* __restrict__ dinv,
    int* __restrict__ es, int PS, int CAPB, int CAPE, int n) {
  __shared__ int sdeg[256];
  __shared__ int sbuf[2][256];
  __shared__ int scur[256];
  const int p = blockIdx.x;
  const int tid = threadIdx.x;
  const int start = p * CAPB;
  const int cnt = gcur[p * GC_PAD];

  sdeg[tid] = 0;
  __syncthreads();
  for (int i = tid; i < cnt; i += 256)
    atomicAdd(&sdeg[(ebin[start + i] >> 17) & 0xFF], 1);
  __syncthreads();

  int v = sdeg[tid];
  sbuf[0][tid] = v;
  __syncthreads();
  int pi = 0;
  for (int off = 1; off < 256; off <<= 1) {
    int x = sbuf[pi][tid];
    if (tid >= off) x += sbuf[pi][tid - off];
    sbuf[pi ^ 1][tid] = x;
    __syncthreads();
    pi ^= 1;
  }
  int incl = sbuf[pi][tid];
  scur[tid] = incl - v;

  const int node = p * PS + tid;
  if (tid < PS && node < n) {
    ideg[node] = v;
    cursor[node] = p * CAPE + incl;       // row END in es coords
    dinv[node] = rsqrtf((float)(v + 1));  // +1 self-loop
  }
  __syncthreads();

  for (int i = tid; i < cnt; i += 256) {
    unsigned pk = ebin[start + i];
    int l = (int)((pk >> 17) & 0xFF);
    int pos = atomicAdd(&scur[l], 1);  // LDS atomic
    es[p * CAPE + pos] = (int)(pk & 0x1FFFFu);
  }
}

// xs split layout: main[n][32 fp16] (64B, line-aligned) + tail[n][8 fp16] (16B).
// Thread i: node i/5, part i%5. parts 0-3 -> main quarter, part 4 -> tail.
__global__ void k_prescale(const float4* __restrict__ x4, const float* __restrict__ dinv,
                           uint4* __restrict__ xs_m, uint4* __restrict__ xs_t, int n5) {
  int i = blockIdx.x * blockDim.x + threadIdx.x;
  if (i < n5) {
    int node = i / 5, part = i - node * 5;
    float w = dinv[node];
    float4 va = x4[node * 10 + part * 2];
    float4 vb = x4[node * 10 + part * 2 + 1];
    __half2 h0 = __float22half2_rn(make_float2(va.x * w, va.y * w));
    __half2 h1 = __float22half2_rn(make_float2(va.z * w, va.w * w));
    __half2 h2 = __float22half2_rn(make_float2(vb.x * w, vb.y * w));
    __half2 h3 = __float22half2_rn(make_float2(vb.z * w, vb.w * w));
    uint4 u;
    u.x = *(unsigned*)&h0; u.y = *(unsigned*)&h1;
    u.z = *(unsigned*)&h2; u.w = *(unsigned*)&h3;
    if (part < 4) xs_m[(size_t)node * 4 + part] = u;
    else xs_t[node] = u;
  }
}

// ---------- Gather + fused linear. 12 nodes/wave, 5 lanes/node.
// pos 0-3 gather one 64B-aligned line quarter from main; pos 4 gathers the
// 16B tail (1.6MB array, L2-resident). 1 heavy line per edge instead of 2. ----------
template <int OUT_HALF>
__global__ __launch_bounds__(256) void k_layer(
    const uint4* __restrict__ in_m, const uint4* __restrict__ in_t,
    const int* __restrict__ es, const int* __restrict__ ideg,
    const int* __restrict__ cursor, const float* __restrict__ dinv,
    const float* __restrict__ W, const float* __restrict__ bias,
    float* __restrict__ outf, __half2* __restrict__ outh_m,
    __half2* __restrict__ outh_t, int n) {
  __shared__ float sWT[DD * SWT_LD];
  __shared__ float sb[DD];
  __shared__ float srow[48][SROW_LD];
  const int tid = threadIdx.x;

  const int w = tid >> 6, lane = tid & 63;
  const int g = lane / 5, pos = lane - g * 5;  // g==12 (lanes 60-63) idle
  const int v = blockIdx.x * 48 + w * 12 + g;

  // Per-lane gather base: main quarter (stride 4 uint4) or tail (stride 1).
  const uint4* gbase = (pos < 4) ? (in_m + pos) : in_t;
  const int gshift = (pos < 4) ? 2 : 0;  // index = s << gshift

#define ACC8(U, A)                                   \
  {                                                  \
    const __half2* hh = (const __half2*)&(U);        \
    float2 f0 = __half22float2(hh[0]);               \
    float2 f1 = __half22float2(hh[1]);               \
    float2 f2 = __half22float2(hh[2]);               \
    float2 f3 = __half22float2(hh[3]);               \
    A[0] += f0.x; A[1] += f0.y; A[2] += f1.x;        \
    A[3] += f1.y; A[4] += f2.x; A[5] += f2.y;        \
    A[6] += f3.x; A[7] += f3.y;                      \
  }
#define GLD(S) gbase[(size_t)((S) << gshift)]

  if (g < 12 && v < n) {
    const int e1 = cursor[v];  // row end
    int e = e1 - ideg[v];      // row start
    float a[8], b[8];
    {
      uint4 u = GLD(v);  // self-loop term
      const __half2* hh = (const __half2*)&u;
      float2 f0 = __half22float2(hh[0]);
      float2 f1 = __half22float2(hh[1]);
      float2 f2 = __half22float2(hh[2]);
      float2 f3 = __half22float2(hh[3]);
      a[0] = f0.x; a[1] = f0.y; a[2] = f1.x; a[3] = f1.y;
      a[4] = f2.x; a[5] = f2.y; a[6] = f3.x; a[7] = f3.y;
#pragma unroll
      for (int q = 0; q < 8; ++q) b[q] = 0.f;
    }
    // 8-deep with one-batch index prefetch
    int n0, n1, n2, n3, n4, n5, n6, n7;
    bool have = (e + 7 < e1);
    if (have) {
      n0 = es[e];     n1 = es[e + 1]; n2 = es[e + 2]; n3 = es[e + 3];
      n4 = es[e + 4]; n5 = es[e + 5]; n6 = es[e + 6]; n7 = es[e + 7];
    }
    while (have) {
      int s0 = n0, s1 = n1, s2 = n2, s3 = n3, s4 = n4, s5 = n5, s6 = n6, s7 = n7;
      int en = e + 8;
      have = (en + 7 < e1);
      if (have) {
        n0 = es[en];     n1 = es[en + 1]; n2 = es[en + 2]; n3 = es[en + 3];
        n4 = es[en + 4]; n5 = es[en + 5]; n6 = es[en + 6]; n7 = es[en + 7];
      }
      uint4 u0 = GLD(s0);
      uint4 u1 = GLD(s1);
      uint4 u2 = GLD(s2);
      uint4 u3 = GLD(s3);
      uint4 u4 = GLD(s4);
      uint4 u5 = GLD(s5);
      uint4 u6 = GLD(s6);
      uint4 u7 = GLD(s7);
      ACC8(u0, a); ACC8(u1, b); ACC8(u2, a); ACC8(u3, b);
      ACC8(u4, a); ACC8(u5, b); ACC8(u6, a); ACC8(u7, b);
      e = en;
    }
    for (; e + 3 < e1; e += 4) {
      int s0 = es[e], s1 = es[e + 1], s2 = es[e + 2], s3 = es[e + 3];
      uint4 u0 = GLD(s0);
      uint4 u1 = GLD(s1);
      uint4 u2 = GLD(s2);
      uint4 u3 = GLD(s3);
      ACC8(u0, a); ACC8(u1, b); ACC8(u2, a); ACC8(u3, b);
    }
    for (; e < e1; ++e) {
      uint4 uu = GLD(es[e]);
      ACC8(uu, a);
    }
    float* r = &srow[w * 12 + g][pos * 8];
#pragma unroll
    for (int q = 0; q < 8; ++q) r[q] = a[q] + b[q];
  }

  // Stage W/bias after gather
  for (int t = tid; t < DD * DD; t += 256) sWT[(t % DD) * SWT_LD + t / DD] = W[t];
  if (tid < DD) sb[tid] = bias[tid];
  __syncthreads();

  if (OUT_HALF) {
    for (int i = tid; i < 48 * 20; i += 256) {
      int l = i / 20, jj = i - l * 20;
      int vv = blockIdx.x * 48 + l;
      if (vv < n) {
        float dv = dinv[vv];
        const float* row = srow[l];
        float s0 = 0.f, s1 = 0.f;
#pragma unroll
        for (int k = 0; k < DD; ++k) {
          s0 = fmaf(row[k], sWT[k * SWT_LD + 2 * jj], s0);
          s1 = fmaf(row[k], sWT[k * SWT_LD + 2 * jj + 1], s1);
        }
        s0 = fmaf(s0, dv, sb[2 * jj]);
        s1 = fmaf(s1, dv, sb[2 * jj + 1]);
        s0 = fmaxf(s0, 0.f) * dv;  // relu + next-layer prescale
        s1 = fmaxf(s1, 0.f) * dv;
        __half2 hv = __float22half2_rn(make_float2(s0, s1));
        if (jj < 16) outh_m[(size_t)vv * 16 + jj] = hv;
        else outh_t[(size_t)vv * 4 + (jj - 16)] = hv;
      }
    }
  } else {
    for (int i = tid; i < 48 * DD; i += 256) {
      int l = i / DD, j = i - l * DD;
      int vv = blockIdx.x * 48 + l;
      if (vv < n) {
        float dv = dinv[vv];
        const float* row = srow[l];
        float acc = 0.f;
#pragma unroll
        for (int k = 0; k < DD; ++k) acc = fmaf(row[k], sWT[k * SWT_LD + j], acc);
        outf[(size_t)vv * DD + j] = fmaf(acc, dv, sb[j]);
      }
    }
  }
#undef GLD
#undef ACC8
}

extern "C" void kernel_launch(void* const* d_in, const int* in_sizes, int n_in,
                              void* d_out, int out_size, void* d_ws, size_t ws_size,
                              hipStream_t stream) {
  const float* x = (const float*)d_in[0];
  const int* ei = (const int*)d_in[1];
  const float* W1 = (const float*)d_in[2];
  const float* b1 = (const float*)d_in[3];
  const float* W2 = (const float*)d_in[4];
  const float* b2 = (const float*)d_in[5];

  const int n = in_sizes[0] / DD;  // 100000
  const int E = in_sizes[1] / 2;   // 1600000
  const int* src = ei;
  const int* dst = ei + E;
  const int PS = (n + NP - 1) / NP;  // 196 local nodes/partition
  const unsigned M = (unsigned)((((unsigned long long)1 << 31) + PS - 1) / PS);
  const int CAPB = E / NP + 512;
  const int CAPE = CAPB;
  const int NCH = (E + BAE - 1) / BAE;  // 196 blocks

  float* out = (float*)d_out;

  // ws (~24.7 MB): dinv | ideg | cursor | gcur | ebin(∪hs_m+hs_t) | es | xs_m | xs_t
  char* w = (char*)d_ws;
  float* dinv = (float*)w;   w += (size_t)n * 4;
  int* ideg = (int*)w;       w += (size_t)n * 4;
  int* cursor = (int*)w;     w += (size_t)n * 4;
  int* gcur = (int*)w;       w += (size_t)NP * GC_PAD * 4;
  char* ebin_hs = w;         w += (size_t)n * 80;          // max(ebin 7.45MB, hs 8MB)
  int* es = (int*)w;         w += (size_t)NP * CAPE * 4;
  uint4* xs_m = (uint4*)w;   w += (size_t)n * 64;
  uint4* xs_t = (uint4*)w;   w += (size_t)n * 16;

  unsigned* ebin = (unsigned*)ebin_hs;
  uint4* hs_m = (uint4*)ebin_hs;                    // live after partB consumed ebin
  uint4* hs_t = (uint4*)(ebin_hs + (size_t)n * 64);

  hipMemsetAsync(gcur, 0, (size_t)NP * GC_PAD * 4, stream);

  k_binA<<<NCH, 256, 0, stream>>>(src, dst, gcur, ebin, E, PS, M, CAPB);
  k_partB<<<NP, 256, 0, stream>>>(ebin, gcur, ideg, cursor, dinv, es, PS, CAPB, CAPE, n);
  const int n5 = n * 5;
  k_prescale<<<(n5 + 255) / 256, 256, 0, stream>>>((const float4*)x, dinv, xs_m, xs_t, n5);

  const int NBK = (n + 47) / 48;
  k_layer<1><<<NBK, 256, 0, stream>>>(xs_m, xs_t, es, ideg, cursor, dinv, W1, b1,
                                      nullptr, (__half2*)hs_m, (__half2*)hs_t, n);
  k_layer<0><<<NBK, 256, 0, stream>>>(hs_m, hs_t, es, ideg, cursor, dinv, W2, b2,
                                      out, nullptr, nullptr, n);
}